// Round 3
// baseline (96.885 us; speedup 1.0000x reference)
//
#include <hip/hip_runtime.h>

// Chamfer distance, B=16, N=M=4096, D=3, fp32.
// v4: tri-round fit shows all VALU math so far ran at 4 cyc/wave-inst
// (pk_fma=8): R0/R1/R2 all = 114.7K cyc/SIMD = 47.8us. Either VOP3 3-src
// ops issue at half rate, or the compiler's under-allocation (52 VGPR vs
// ~90 live) stalls the stream. This version hedges both:
//  - chain d = fmac(mz,z, fmac(my,y, fma(mx,x,w))): 1 VOP3 + 2 VOP2 per
//    target instead of 3 VOP3 (w-add folded into the first fma addend).
//  - min via fminf(fminf()) -> v_min3 fusion, no inline asm anywhere.
//  - QPL=8: ~60 live VGPRs, no register gymnastics possible.
//  - 1024 blocks = 4/CU ~= 8 waves/SIMD to absorb dependency stalls.
// Partial mins across 4 target-chunks combined via monotone uint atomicMin
// (all values >= 0), out pre-filled with +inf bits by init_out.

#define CB 16
#define CN 4096
#define CM 4096
#define QPL 8               // queries per lane
#define WVS 8               // waves per block (512 threads)
#define QPB (64 * QPL)      // queries per block = 512
#define TPB 1024            // targets per block (quarter cloud)
#define GPB (TPB / 2)       // pair-groups per block = 512
#define GRP_PW (GPB / WVS)  // groups per wave = 64

typedef float v4f __attribute__((ext_vector_type(4)));

// One pair-group (2 targets) vs one query.
// Group format: t0 = (x0,x1,y0,y1), t1 = (z0,z1,w0,w1), w = |t|^2.
// d_j = w_j - 2(qx*x_j + qy*y_j + qz*z_j); |q|^2 added in the epilogue.
// First op is a true fma (addend = w); the two follow-ups accumulate into
// the destination so the compiler can emit v_fmac_f32 (VOP2).
__device__ __forceinline__ void grp(const v4f t0, const v4f t1,
                                    float mx, float my, float mz, float& best)
{
    float d0 = fmaf(mx, t0.x, t1.z);   // v_fma  (VOP3)
    float d1 = fmaf(mx, t0.y, t1.w);   // v_fma  (VOP3)
    d0 = fmaf(my, t0.z, d0);           // v_fmac (VOP2)
    d1 = fmaf(my, t0.w, d1);           // v_fmac (VOP2)
    d0 = fmaf(mz, t1.x, d0);           // v_fmac (VOP2)
    d1 = fmaf(mz, t1.y, d1);           // v_fmac (VOP2)
    best = fminf(best, fminf(d0, d1)); // v_min3 fusion
}

__global__ void init_out(unsigned* __restrict__ out)
{
    out[blockIdx.x * 512 + threadIdx.x] = 0x7F800000u;  // +inf bits
}

// grid: (8 qtiles x 4 tchunks, 16 batches, 2 dirs) = 1024 blocks x 512 thr.
__global__ __launch_bounds__(512, 4) void chamfer_min(
    const float* __restrict__ x1, const float* __restrict__ x2,
    unsigned* __restrict__ out)
{
    const int dir    = blockIdx.z;
    const int b      = blockIdx.y;
    const int qtile  = blockIdx.x & 7;   // which 512-query tile
    const int tchunk = blockIdx.x >> 3;  // which 1024-target chunk

    const float* __restrict__ qraw = (dir ? x2 : x1) + (size_t)b * CN * 3;
    const float* __restrict__ traw = (dir ? x1 : x2) + (size_t)b * CM * 3
                                   + (size_t)tchunk * TPB * 3;
    unsigned* __restrict__ o = out + (dir ? ((size_t)CB * CN + (size_t)b * CM)
                                          : ((size_t)b * CN)) + qtile * QPB;

    // 16 KB: 512 pair-groups x 2 v4f; reused as red[WVS][QPL][64] (16 KB).
    __shared__ v4f smem[1024];

    const int tid  = threadIdx.x;
    const int lane = tid & 63;
    const int wave = __builtin_amdgcn_readfirstlane(tid >> 6);

    // Load queries: lane handles q = qtile*512 + lane + 64k. Only -2q kept
    // live; |q|^2 recomputed in the epilogue.
    float mx[QPL], my[QPL], mz[QPL];
    #pragma unroll
    for (int k = 0; k < QPL; ++k) {
        const float* qp = qraw + (size_t)3 * (qtile * QPB + lane + 64 * k);
        mx[k] = -2.0f * qp[0];
        my[k] = -2.0f * qp[1];
        mz[k] = -2.0f * qp[2];
    }

    // ---- Stage 1024 targets: threads 0..255 pack targets [4t, 4t+4)
    // into pair-groups 2t, 2t+1.
    if (tid < 256) {
        const v4f* rv = (const v4f*)(traw + (size_t)12 * tid);  // 48B chunks
        v4f r0 = rv[0], r1 = rv[1], r2 = rv[2];
        // r0=(t0x,t0y,t0z,t1x) r1=(t1y,t1z,t2x,t2y) r2=(t2z,t3x,t3y,t3z)
        float w0 = r0.x*r0.x + r0.y*r0.y + r0.z*r0.z;
        float w1 = r0.w*r0.w + r1.x*r1.x + r1.y*r1.y;
        float w2 = r1.z*r1.z + r1.w*r1.w + r2.x*r2.x;
        float w3 = r2.y*r2.y + r2.z*r2.z + r2.w*r2.w;
        smem[4*tid + 0] = (v4f){r0.x, r0.w, r0.y, r1.x};  // x0,x1,y0,y1
        smem[4*tid + 1] = (v4f){r0.z, r1.y, w0, w1};      // z0,z1,w0,w1
        smem[4*tid + 2] = (v4f){r1.z, r2.y, r1.w, r2.z};
        smem[4*tid + 3] = (v4f){r2.x, r2.w, w2, w3};
    }

    float best[QPL];
    #pragma unroll
    for (int k = 0; k < QPL; ++k) best[k] = 1e30f;

    __syncthreads();

    // ---- Scan: wave w handles local groups [w*64, w*64+64).
    const v4f* tp = &smem[wave * GRP_PW * 2];
    #pragma unroll 1
    for (int g = 0; g < GRP_PW; g += 2) {
        v4f a0 = tp[2*g + 0];
        v4f a1 = tp[2*g + 1];
        v4f b0 = tp[2*g + 2];
        v4f b1 = tp[2*g + 3];
        #pragma unroll
        for (int k = 0; k < QPL; ++k)
            grp(a0, a1, mx[k], my[k], mz[k], best[k]);
        #pragma unroll
        for (int k = 0; k < QPL; ++k)
            grp(b0, b1, mx[k], my[k], mz[k], best[k]);
    }
    __syncthreads();

    // ---- Cross-wave min combine (reuse smem as red[WVS][QPL][64] = 16 KB)
    float* red = (float*)smem;
    #pragma unroll
    for (int k = 0; k < QPL; ++k)
        red[(wave * QPL + k) * 64 + lane] = best[k];
    __syncthreads();

    // 512 threads finish 512 outputs: add |q|^2, clamp, atomic-combine the
    // four target-chunks via monotone uint bits.
    {
        const int k = tid >> 6, l = tid & 63;
        float v = red[k * 64 + l];
        #pragma unroll
        for (int w = 1; w < WVS; ++w)
            v = fminf(v, red[(w * QPL + k) * 64 + l]);
        const float* qp = qraw + (size_t)3 * (qtile * QPB + tid);
        const float nq = qp[0]*qp[0] + qp[1]*qp[1] + qp[2]*qp[2];
        const float val = fmaxf(v + nq, 0.0f);
        atomicMin(&o[tid], __float_as_uint(val));
    }
}

extern "C" void kernel_launch(void* const* d_in, const int* in_sizes, int n_in,
                              void* d_out, int out_size, void* d_ws, size_t ws_size,
                              hipStream_t stream) {
    const float* x1 = (const float*)d_in[0];   // [B,N,3]
    const float* x2 = (const float*)d_in[1];   // [B,M,3]
    unsigned* out = (unsigned*)d_out;

    // Fill out with +inf bits, then min-combine from the main kernel.
    init_out<<<dim3(2 * CB * CN / 512), 512, 0, stream>>>(out);
    chamfer_min<<<dim3(32, CB, 2), 512, 0, stream>>>(x1, x2, out);
}

// Round 4
// 81.667 us; speedup vs baseline: 1.1863x; 1.1863x over previous
//
#include <hip/hip_runtime.h>

// Chamfer distance, B=16, N=M=4096, D=3, fp32.
// v5: four rounds of VALU variants (VOP3, VOP2, pk, 3 occupancies, 3 reg
// counts) ALL converge to 4 cyc/wave-inst f32 issue => VALU-only floor is
// ~48us and we were ON it. MfmaUtil was 0.0 all along: move the multiplies
// to the matrix pipe. d = |t|^2 - 2 t.q (+|q|^2 in epilogue) as a K=11 dot
// via mfma_f32_16x16x32_bf16 with fp32->bf16 hi/lo splits (3-term product:
// th*mh + tl*mh + th*ml; dropped tl*ml ~ 2^-18 rel -> ~1e-4 abs error).
// A = 16 targets (rows), B = 16 queries (cols); verified C/D layout
// (col=lane&15, row=(lane>>4)*4+reg) -> per-lane 4 targets x 1 query,
// min-reduce = 2 v_min3 per MFMA + 2 shfl_xor at the end.
// K slots: 0-2 th*mh(x,y,z), 3-5 tl*mh, 6-8 th*ml, 9-10 |t|^2 hi/lo vs 1.0,
// 11-31 zero (kb>=2 lanes read a zero pad).
// Per block: 1024 targets staged as 48B LDS records (padded stride => <=2-way
// bank conflicts), 1024 queries in registers (8 waves x 8 B-frags).
// Grid (4 qtiles x 4 tchunks, 16, 2) = 512 blocks; partial mins across
// tchunks combined via monotone uint atomicMin into +inf-filled out.

#define CB 16
#define CN 4096
#define CM 4096
#define WVS 8
#define NQT 8            // query tiles (of 16) per wave -> 128 queries/wave
#define QPW (NQT * 16)
#define TPB 1024         // targets per block
#define NTT (TPB / 16)   // 64 target tiles
#define RECV4 3          // v4-slots per target record (48 B: 2 used + 1 pad)
#define ZPADV4 (TPB * RECV4)  // zero-pad v4-index (256 B region)

typedef float f32x4 __attribute__((ext_vector_type(4)));
typedef short bf16x8 __attribute__((ext_vector_type(8)));
typedef unsigned int u32;
typedef u32 u32x4 __attribute__((ext_vector_type(4)));
typedef float v4f __attribute__((ext_vector_type(4)));

__device__ __forceinline__ u32 f2bf(float f) {          // RNE f32 -> bf16 bits
    u32 u = __float_as_uint(f);
    return (u + 0x7FFFu + ((u >> 16) & 1u)) >> 16;
}
__device__ __forceinline__ float bf2f(u32 h) { return __uint_as_float(h << 16); }

__global__ void init_out(unsigned* __restrict__ out)
{
    out[blockIdx.x * 512 + threadIdx.x] = 0x7F800000u;  // +inf bits
}

__global__ __launch_bounds__(512, 4) void chamfer_mfma(
    const float* __restrict__ x1, const float* __restrict__ x2,
    unsigned* __restrict__ out)
{
    const int dir    = blockIdx.z;
    const int b      = blockIdx.y;
    const int qtile  = blockIdx.x & 3;   // 1024-query tile
    const int tchunk = blockIdx.x >> 2;  // 1024-target chunk

    const float* __restrict__ qraw = (dir ? x2 : x1) + (size_t)b * CN * 3;
    const float* __restrict__ traw = (dir ? x1 : x2) + (size_t)b * CM * 3
                                   + (size_t)tchunk * TPB * 3;
    unsigned* __restrict__ o = out + (dir ? ((size_t)CB * CN + (size_t)b * CM)
                                          : ((size_t)b * CN)) + qtile * 1024;

    __shared__ u32x4 ldsv[TPB * RECV4 + 16];   // 48 KB records + 256 B zeros

    const int tid  = threadIdx.x;
    const int lane = tid & 63;
    const int wave = __builtin_amdgcn_readfirstlane(tid >> 6);
    const int row  = lane & 15;
    const int kb   = lane >> 4;

    // ---- Stage 1024 targets: threads 0..255 pack targets [4t,4t+4) into
    // 48B records: v4#0 = bf16{txh,tyh | tzh,txl | tyl,tzl | txh,tyh},
    //              v4#1 = bf16{tzh,nth | ntl,0 | 0 | 0}, v4#2 = pad.
    if (tid < 256) {
        const v4f* rv = (const v4f*)(traw + (size_t)12 * tid);
        v4f r0 = rv[0], r1 = rv[1], r2 = rv[2];
        const float tx[4] = {r0.x, r0.w, r1.z, r2.y};
        const float ty[4] = {r0.y, r1.x, r1.w, r2.z};
        const float tz[4] = {r0.z, r1.y, r2.x, r2.w};
        #pragma unroll
        for (int i = 0; i < 4; ++i) {
            float X = tx[i], Y = ty[i], Z = tz[i];
            u32 xh = f2bf(X), yh = f2bf(Y), zh = f2bf(Z);
            u32 xl = f2bf(X - bf2f(xh));
            u32 yl = f2bf(Y - bf2f(yh));
            u32 zl = f2bf(Z - bf2f(zh));
            float nt = fmaf(X, X, fmaf(Y, Y, Z * Z));
            u32 nh = f2bf(nt), nl = f2bf(nt - bf2f(nh));
            const int r = 4 * tid + i;
            ldsv[r * RECV4 + 0] = (u32x4){xh | (yh << 16), zh | (xl << 16),
                                          yl | (zl << 16), xh | (yh << 16)};
            ldsv[r * RECV4 + 1] = (u32x4){zh | (nh << 16), nl, 0u, 0u};
        }
    }
    if (tid < 16) ldsv[ZPADV4 + tid] = (u32x4){0u, 0u, 0u, 0u};

    // ---- Queries: wave covers [qtile*1024 + wave*128, +128). Per qt, lane's
    // col = row. B-frag by kb: kb0 = {mxh,myh | mzh,mxh | myh,mzh | mxl,myl},
    // kb1 = {mzl,1 | 1,0 | 0 | 0}, kb>=2 zero. (m = -2q, hi/lo split.)
    const int qbase = qtile * 1024 + wave * QPW;
    bf16x8 bq[NQT];
    float nq[NQT];
    #pragma unroll
    for (int qt = 0; qt < NQT; ++qt) {
        const float* qp = qraw + (size_t)3 * (qbase + qt * 16 + row);
        float qx = qp[0], qy = qp[1], qz = qp[2];
        nq[qt] = fmaf(qx, qx, fmaf(qy, qy, qz * qz));
        float MX = -2.f * qx, MY = -2.f * qy, MZ = -2.f * qz;
        u32 xh = f2bf(MX), yh = f2bf(MY), zh = f2bf(MZ);
        u32 xl = f2bf(MX - bf2f(xh));
        u32 yl = f2bf(MY - bf2f(yh));
        u32 zl = f2bf(MZ - bf2f(zh));
        u32x4 w;
        if (kb == 0)
            w = (u32x4){xh | (yh << 16), zh | (xh << 16),
                        yh | (zh << 16), xl | (yl << 16)};
        else if (kb == 1)
            w = (u32x4){zl | (0x3F80u << 16), 0x3F80u, 0u, 0u};
        else
            w = (u32x4){0u, 0u, 0u, 0u};
        bq[qt] = __builtin_bit_cast(bf16x8, w);
    }

    __syncthreads();

    // ---- Sweep 64 target tiles: per tile 1 ds_read_b128 (A-frag) + 8 MFMA
    // + 16 fused min3. kb<2 lanes walk the records; kb>=2 read the zero pad.
    u32 a_idx = (kb < 2) ? (u32)(row * RECV4 + kb) : (u32)(ZPADV4 + row);
    const u32 a_step = (kb < 2) ? (u32)(16 * RECV4) : 0u;

    float best[NQT];
    #pragma unroll
    for (int qt = 0; qt < NQT; ++qt) best[qt] = 1e30f;

    #pragma unroll 1
    for (int t = 0; t < NTT; ++t) {
        bf16x8 af = __builtin_bit_cast(bf16x8, ldsv[a_idx]);
        a_idx += a_step;
        #pragma unroll
        for (int qt = 0; qt < NQT; ++qt) {
            f32x4 acc = __builtin_amdgcn_mfma_f32_16x16x32_bf16(
                af, bq[qt], (f32x4){0.f, 0.f, 0.f, 0.f}, 0, 0, 0);
            best[qt] = fminf(fminf(best[qt], acc.x), acc.y);  // v_min3
            best[qt] = fminf(fminf(best[qt], acc.z), acc.w);  // v_min3
        }
    }

    // ---- Reduce across the 4 kb lane-groups (rows 0..15 of each tile),
    // add |q|^2, clamp, atomic-combine the 4 target chunks.
    #pragma unroll
    for (int qt = 0; qt < NQT; ++qt) {
        float v = best[qt];
        v = fminf(v, __shfl_xor(v, 16));
        v = fminf(v, __shfl_xor(v, 32));
        if (kb == 0) {
            float val = fmaxf(v + nq[qt], 0.f);
            atomicMin(o + wave * QPW + qt * 16 + row, __float_as_uint(val));
        }
    }
}

extern "C" void kernel_launch(void* const* d_in, const int* in_sizes, int n_in,
                              void* d_out, int out_size, void* d_ws, size_t ws_size,
                              hipStream_t stream) {
    const float* x1 = (const float*)d_in[0];   // [B,N,3]
    const float* x2 = (const float*)d_in[1];   // [B,M,3]
    unsigned* out = (unsigned*)d_out;

    init_out<<<dim3(2 * CB * CN / 512), 512, 0, stream>>>(out);
    chamfer_mfma<<<dim3(16, CB, 2), 512, 0, stream>>>(x1, x2, out);
}

// Round 6
// 80.003 us; speedup vs baseline: 1.2110x; 1.0208x over previous
//
#include <hip/hip_runtime.h>

// Chamfer distance, B=16, N=M=4096, D=3, fp32.
// v7: revert to the VERIFIED 16x16x32 MFMA numerics (R4 passed, 0.0078
// absmax; R5's 32x32x16 failed -> its A/B fragment k-mappings differ, do
// not probe blind). Keep R5's ILP/occupancy structure:
//  - NQT=4 (64 q/wave) + __launch_bounds__(512,8): ~50 live VGPRs, cap 64
//    -> 8 waves/SIMD (R4 had 4) for stall hiding.
//  - register double-buffer of the A-frag ds_read (prefetch t+1).
//  - two independent min-accumulators per qt (acc.x,y -> best0; z,w ->
//    best1): no serial min3 chain per tile.
//  - LDS layout [tile][64 lanes] incl. zero rows for kb>=2: wave ds_read_b128
//    spans 1024 contiguous bytes (conflict-free); staging = 1 target/thread,
//    4 uniform ds_write_b128, branch-free.
// Numerics (R4-verified): d = |t|^2 - 2 t.q via K=11 bf16 hi/lo 3-term
// split (th*mh + tl*mh + th*ml; dropped tl*ml ~2^-18). A-lane = kb*16+row
// holds K slots kb*8+j; same for B. K0-7: {xh,yh,zh,xl,yl,zl,xh,yh} (A) vs
// {mhx,mhy,mhz,mhx,mhy,mhz,mlx,mly} (B); K8-15: {zh,nh,nl,0..} vs
// {mlz,1,1,0..}; kb>=2 zero. |q|^2 added in fp32 epilogue. C/D map (m89):
// col=lane&15, row=(lane>>4)*4+reg -> min over 4 regs + shfl_xor(16,32).
// Partial mins across 8 target-chunks merged via monotone uint atomicMin
// into +inf-prefilled out (all values >= 0).

#define CB 16
#define CN 4096
#define CM 4096
#define WVS 8
#define NQT 4                // query tiles (of 16) per wave
#define QPW (NQT * 16)       // 64 queries per wave
#define QPB (WVS * QPW)      // 512 queries per block
#define TPB 512              // targets per block
#define NTT (TPB / 16)       // 32 target tiles

typedef float f32x4 __attribute__((ext_vector_type(4)));
typedef short bf16x8 __attribute__((ext_vector_type(8)));
typedef unsigned int u32;
typedef u32 u32x4 __attribute__((ext_vector_type(4)));

__device__ __forceinline__ u32 f2bf(float f) {          // RNE f32 -> bf16 bits
    u32 u = __float_as_uint(f);
    return (u + 0x7FFFu + ((u >> 16) & 1u)) >> 16;
}
__device__ __forceinline__ float bf2f(u32 h) { return __uint_as_float(h << 16); }

__global__ void init_out(unsigned* __restrict__ out)
{
    out[blockIdx.x * 512 + threadIdx.x] = 0x7F800000u;  // +inf bits
}

// grid: (8 qtiles x 8 tchunks, 16 batches, 2 dirs) = 2048 blocks x 512 thr.
__global__ __launch_bounds__(512, 8) void chamfer_mfma(
    const float* __restrict__ x1, const float* __restrict__ x2,
    unsigned* __restrict__ out)
{
    const int dir    = blockIdx.z;
    const int b      = blockIdx.y;
    const int qtile  = blockIdx.x & 7;   // 512-query tile
    const int tchunk = blockIdx.x >> 3;  // 512-target chunk

    const float* __restrict__ qraw = (dir ? x2 : x1) + (size_t)b * CN * 3;
    const float* __restrict__ traw = (dir ? x1 : x2) + (size_t)b * CM * 3
                                   + (size_t)tchunk * TPB * 3;
    unsigned* __restrict__ o = out + (dir ? ((size_t)CB * CN + (size_t)b * CM)
                                          : ((size_t)b * CN)) + qtile * QPB;

    // [tile][64]: lanes 0-15 kb0 records, 16-31 kb1, 32-63 zeros. 32 KB.
    __shared__ u32x4 AI[NTT * 64];

    const int tid  = threadIdx.x;
    const int lane = tid & 63;
    const int wave = __builtin_amdgcn_readfirstlane(tid >> 6);
    const int row  = lane & 15;
    const int kb   = lane >> 4;

    // ---- Stage: thread tid packs target tid (1 per thread, branch-free).
    {
        const float* tp3 = traw + 3 * tid;
        float X = tp3[0], Y = tp3[1], Z = tp3[2];
        u32 xh = f2bf(X), yh = f2bf(Y), zh = f2bf(Z);
        u32 xl = f2bf(X - bf2f(xh));
        u32 yl = f2bf(Y - bf2f(yh));
        u32 zl = f2bf(Z - bf2f(zh));
        float nt = fmaf(X, X, fmaf(Y, Y, Z * Z));
        u32 nh = f2bf(nt), nl = f2bf(nt - bf2f(nh));
        const int base = (tid >> 4) * 64 + (tid & 15);
        AI[base +  0] = (u32x4){xh | (yh << 16), zh | (xl << 16),
                                yl | (zl << 16), xh | (yh << 16)};
        AI[base + 16] = (u32x4){zh | (nh << 16), nl, 0u, 0u};
        AI[base + 32] = (u32x4){0u, 0u, 0u, 0u};
        AI[base + 48] = (u32x4){0u, 0u, 0u, 0u};
    }

    // ---- Queries: wave covers [qtile*512 + wave*64, +64); lane's col = row.
    // B-frag kb0: {mhx,mhy | mhz,mhx | mhy,mhz | mlx,mly}
    //        kb1: {mlz,1.0 | 1.0,0 | 0,0 | 0,0}; kb>=2 zero.  (m = -2q)
    bf16x8 bq[NQT];
    float nq[NQT];
    #pragma unroll
    for (int qt = 0; qt < NQT; ++qt) {
        const float* qp = qraw
            + (size_t)3 * (qtile * QPB + wave * QPW + qt * 16 + row);
        float qx = qp[0], qy = qp[1], qz = qp[2];
        nq[qt] = fmaf(qx, qx, fmaf(qy, qy, qz * qz));
        float MX = -2.f * qx, MY = -2.f * qy, MZ = -2.f * qz;
        u32 xh = f2bf(MX), yh = f2bf(MY), zh = f2bf(MZ);
        u32 xl = f2bf(MX - bf2f(xh));
        u32 yl = f2bf(MY - bf2f(yh));
        u32 zl = f2bf(MZ - bf2f(zh));
        u32x4 w;
        if (kb == 0)
            w = (u32x4){xh | (yh << 16), zh | (xh << 16),
                        yh | (zh << 16), xl | (yl << 16)};
        else if (kb == 1)
            w = (u32x4){zl | (0x3F80u << 16), 0x3F80u, 0u, 0u};
        else
            w = (u32x4){0u, 0u, 0u, 0u};
        bq[qt] = __builtin_bit_cast(bf16x8, w);
    }

    float best0[NQT], best1[NQT];
    #pragma unroll
    for (int qt = 0; qt < NQT; ++qt) { best0[qt] = 1e30f; best1[qt] = 1e30f; }

    __syncthreads();

    // ---- Sweep 32 tiles: per iter 1 prefetched ds_read_b128 (conflict-free,
    // contiguous 1 KB/wave) + 4 independent MFMA + 8 independent min3.
    const u32x4* ap = &AI[lane];
    bf16x8 af = __builtin_bit_cast(bf16x8, ap[0]);
    #pragma unroll 1
    for (int t = 0; t < NTT; ++t) {
        bf16x8 afn = __builtin_bit_cast(bf16x8, ap[((t + 1) & (NTT - 1)) * 64]);
        #pragma unroll
        for (int qt = 0; qt < NQT; ++qt) {
            f32x4 acc = __builtin_amdgcn_mfma_f32_16x16x32_bf16(
                af, bq[qt], (f32x4){0.f, 0.f, 0.f, 0.f}, 0, 0, 0);
            best0[qt] = fminf(fminf(best0[qt], acc.x), acc.y);  // v_min3
            best1[qt] = fminf(fminf(best1[qt], acc.z), acc.w);  // v_min3
        }
        af = afn;
    }

    // ---- Reduce kb groups (rows 0-15 per tile), add |q|^2, clamp, merge.
    #pragma unroll
    for (int qt = 0; qt < NQT; ++qt) {
        float v = fminf(best0[qt], best1[qt]);
        v = fminf(v, __shfl_xor(v, 16));
        v = fminf(v, __shfl_xor(v, 32));
        if (kb == 0) {
            float val = fmaxf(v + nq[qt], 0.f);
            atomicMin(o + wave * QPW + qt * 16 + row, __float_as_uint(val));
        }
    }
}

extern "C" void kernel_launch(void* const* d_in, const int* in_sizes, int n_in,
                              void* d_out, int out_size, void* d_ws, size_t ws_size,
                              hipStream_t stream) {
    const float* x1 = (const float*)d_in[0];   // [B,N,3]
    const float* x2 = (const float*)d_in[1];   // [B,M,3]
    unsigned* out = (unsigned*)d_out;

    init_out<<<dim3(2 * CB * CN / 512), 512, 0, stream>>>(out);
    chamfer_mfma<<<dim3(64, CB, 2), 512, 0, stream>>>(x1, x2, out);
}